// Round 1
// baseline (1458.678 us; speedup 1.0000x reference)
//
#include <hip/hip_runtime.h>
#include <math.h>

#define Bb 8
#define Nn 2048
#define Mm 2048
#define Dd 256
#define TOPK 128
#define SK_ITERS 20
#define NCH 32            // n-chunks for v-update partials
#define CHROWS (Nn/NCH)   // 64
#define NEG_INIT (-1e30f)
// -1/(eps*ln2): cost -> log2-domain scaled score
#define SCALE_L2 (-1442.6950408889634f)

// ---------------- init: marginals -> log2 p / log2 q, Ve = 0 ----------------
__global__ void wl_init_kernel(const float* __restrict__ src_o, const float* __restrict__ tgt_o,
                               float* __restrict__ logp2, float* __restrict__ logq2,
                               float* __restrict__ Ve) {
    __shared__ float lds[8];
    int b = blockIdx.x, t = threadIdx.x;
    int l = t & 63, w = t >> 6;
    float s = 0.f, q = 0.f;
    for (int i = t; i < Nn; i += 256) s += src_o[b * Nn + i];
    for (int i = t; i < Mm; i += 256) q += tgt_o[b * Mm + i];
    for (int o = 32; o; o >>= 1) { s += __shfl_xor(s, o); q += __shfl_xor(q, o); }
    if (l == 0) { lds[w] = s; lds[4 + w] = q; }
    __syncthreads();
    float ssum = fmaxf(lds[0] + lds[1] + lds[2] + lds[3], 1e-4f);
    float qsum = fmaxf(lds[4] + lds[5] + lds[6] + lds[7], 1e-4f);
    float rs = 1.f / ssum, rq = 1.f / qsum;
    for (int i = t; i < Nn; i += 256) logp2[b * Nn + i] = log2f(src_o[b * Nn + i] * rs);
    for (int i = t; i < Mm; i += 256) { logq2[b * Mm + i] = log2f(tgt_o[b * Mm + i] * rq); Ve[b * Mm + i] = 0.f; }
}

// ---------------- squared row norms ----------------
__global__ void wl_norms_kernel(const float* __restrict__ feats, float* __restrict__ out) {
    int w = threadIdx.x >> 6, l = threadIdx.x & 63;
    int row = blockIdx.x * 4 + w;             // [0, B*2048)
    float4 f = ((const float4*)(feats + (size_t)row * Dd))[l];
    float s = f.x * f.x + f.y * f.y + f.z * f.z + f.w * f.w;
    for (int o = 32; o; o >>= 1) s += __shfl_xor(s, o);
    if (l == 0) out[row] = s;
}

// ---------------- cost GEMM: Sc = -||fx - fy|| / (eps*ln2) ----------------
#define BT 128
#define KT 32
#define LDT 132
__global__ __launch_bounds__(256)
void wl_cost_kernel(const float* __restrict__ A, const float* __restrict__ Bf,
                    const float* __restrict__ nx, const float* __restrict__ ny,
                    float* __restrict__ Sc) {
    __shared__ float As[KT][LDT];
    __shared__ float Bs[KT][LDT];
    int b = blockIdx.z;
    int n0 = blockIdx.y * BT, m0 = blockIdx.x * BT;
    const float* Ab = A + (size_t)b * Nn * Dd;
    const float* Bbp = Bf + (size_t)b * Mm * Dd;
    int t = threadIdx.x;
    int w = t >> 6, l = t & 63;
    int tx = (w & 1) * 8 + (l & 7);   // 0..15 col group
    int ty = (w >> 1) * 8 + (l >> 3); // 0..15 row group
    float acc[8][8] = {};
    for (int k0 = 0; k0 < Dd; k0 += KT) {
        __syncthreads();
#pragma unroll
        for (int i = 0; i < 4; i++) {
            int c = t + 256 * i;          // 0..1023
            int row = c >> 3, kc = (c & 7) << 2;
            float4 v = *(const float4*)(Ab + (size_t)(n0 + row) * Dd + k0 + kc);
            As[kc + 0][row] = v.x; As[kc + 1][row] = v.y; As[kc + 2][row] = v.z; As[kc + 3][row] = v.w;
            float4 u = *(const float4*)(Bbp + (size_t)(m0 + row) * Dd + k0 + kc);
            Bs[kc + 0][row] = u.x; Bs[kc + 1][row] = u.y; Bs[kc + 2][row] = u.z; Bs[kc + 3][row] = u.w;
        }
        __syncthreads();
#pragma unroll 4
        for (int k = 0; k < KT; k++) {
            float4 a0 = *(const float4*)&As[k][ty * 8];
            float4 a1 = *(const float4*)&As[k][ty * 8 + 4];
            float4 b0 = *(const float4*)&Bs[k][tx * 8];
            float4 b1 = *(const float4*)&Bs[k][tx * 8 + 4];
            float a[8] = { a0.x, a0.y, a0.z, a0.w, a1.x, a1.y, a1.z, a1.w };
            float bv[8] = { b0.x, b0.y, b0.z, b0.w, b1.x, b1.y, b1.z, b1.w };
#pragma unroll
            for (int i = 0; i < 8; i++)
#pragma unroll
                for (int j = 0; j < 8; j++)
                    acc[i][j] = fmaf(a[i], bv[j], acc[i][j]);
        }
    }
    float nyv[8];
#pragma unroll
    for (int j = 0; j < 8; j++) nyv[j] = ny[b * Mm + m0 + tx * 8 + j];
#pragma unroll
    for (int i = 0; i < 8; i++) {
        int n = n0 + ty * 8 + i;
        float nxv = nx[b * Nn + n];
        float o[8];
#pragma unroll
        for (int j = 0; j < 8; j++) {
            float d2 = nxv + nyv[j] - 2.f * acc[i][j];
            d2 = fmaxf(d2, 0.f);
            float c = d2 > 0.f ? sqrtf(d2) : 0.f;
            o[j] = SCALE_L2 * c;
        }
        float* orow = Sc + ((size_t)b * Nn + n) * Mm + m0 + tx * 8;
        *(float4*)orow = make_float4(o[0], o[1], o[2], o[3]);
        *(float4*)(orow + 4) = make_float4(o[4], o[5], o[6], o[7]);
    }
}

// ---------------- u-update: Ue = logp2 - LSE2_m(Sc + Ve) ----------------
__global__ __launch_bounds__(256)
void wl_u_kernel(const float* __restrict__ Sc, const float* __restrict__ Ve,
                 const float* __restrict__ logp2, float* __restrict__ Ue) {
    int w = threadIdx.x >> 6, l = threadIdx.x & 63;
    int row = blockIdx.x * 4 + w;         // [0, B*N)
    int b = row >> 11;
    const float4* s4 = (const float4*)(Sc + (size_t)row * Mm);
    const float4* v4 = (const float4*)(Ve + (size_t)b * Mm);
    float mx0 = NEG_INIT, mx1 = NEG_INIT, mx2 = NEG_INIT, mx3 = NEG_INIT;
    float sm0 = 0.f, sm1 = 0.f, sm2 = 0.f, sm3 = 0.f;
#pragma unroll
    for (int i = 0; i < 8; i++) {
        int c = l + 64 * i;
        float4 sv = s4[c]; float4 vv = v4[c];
        float t0 = sv.x + vv.x, t1 = sv.y + vv.y, t2 = sv.z + vv.z, t3 = sv.w + vv.w;
        float n0 = fmaxf(mx0, t0); sm0 = sm0 * exp2f(mx0 - n0) + exp2f(t0 - n0); mx0 = n0;
        float n1 = fmaxf(mx1, t1); sm1 = sm1 * exp2f(mx1 - n1) + exp2f(t1 - n1); mx1 = n1;
        float n2 = fmaxf(mx2, t2); sm2 = sm2 * exp2f(mx2 - n2) + exp2f(t2 - n2); mx2 = n2;
        float n3 = fmaxf(mx3, t3); sm3 = sm3 * exp2f(mx3 - n3) + exp2f(t3 - n3); mx3 = n3;
    }
    float mx = fmaxf(fmaxf(mx0, mx1), fmaxf(mx2, mx3));
    float sm = sm0 * exp2f(mx0 - mx) + sm1 * exp2f(mx1 - mx) + sm2 * exp2f(mx2 - mx) + sm3 * exp2f(mx3 - mx);
    for (int o = 32; o; o >>= 1) {
        float om = __shfl_xor(mx, o), os = __shfl_xor(sm, o);
        float nm = fmaxf(mx, om);
        sm = sm * exp2f(mx - nm) + os * exp2f(om - nm);
        mx = nm;
    }
    if (l == 0) Ue[row] = logp2[row] - (mx + log2f(sm));
}

// ---------------- v-update partials over n-chunks ----------------
__global__ __launch_bounds__(256)
void wl_v_partial_kernel(const float* __restrict__ Sc, const float* __restrict__ Ue,
                         float* __restrict__ pmx, float* __restrict__ psm) {
    int b = blockIdx.z, ch = blockIdx.y;
    int m0 = blockIdx.x * 1024 + threadIdx.x * 4;
    const float* base = Sc + (size_t)b * Nn * Mm;
    const float* ue = Ue + b * Nn;
    float mx0 = NEG_INIT, mx1 = NEG_INIT, mx2 = NEG_INIT, mx3 = NEG_INIT;
    float sm0 = 0.f, sm1 = 0.f, sm2 = 0.f, sm3 = 0.f;
    int nst = ch * CHROWS;
#pragma unroll 4
    for (int n = nst; n < nst + CHROWS; n++) {
        float u = ue[n];
        float4 sv = *(const float4*)(base + (size_t)n * Mm + m0);
        float t0 = sv.x + u, t1 = sv.y + u, t2 = sv.z + u, t3 = sv.w + u;
        float n0 = fmaxf(mx0, t0); sm0 = sm0 * exp2f(mx0 - n0) + exp2f(t0 - n0); mx0 = n0;
        float n1 = fmaxf(mx1, t1); sm1 = sm1 * exp2f(mx1 - n1) + exp2f(t1 - n1); mx1 = n1;
        float n2 = fmaxf(mx2, t2); sm2 = sm2 * exp2f(mx2 - n2) + exp2f(t2 - n2); mx2 = n2;
        float n3 = fmaxf(mx3, t3); sm3 = sm3 * exp2f(mx3 - n3) + exp2f(t3 - n3); mx3 = n3;
    }
    size_t pi = ((size_t)(b * NCH + ch)) * Mm + m0;
    *(float4*)(pmx + pi) = make_float4(mx0, mx1, mx2, mx3);
    *(float4*)(psm + pi) = make_float4(sm0, sm1, sm2, sm3);
}

// ---------------- v-update combine: Ve = logq2 - LSE2_n ----------------
__global__ void wl_v_combine_kernel(const float* __restrict__ pmx, const float* __restrict__ psm,
                                    const float* __restrict__ logq2, float* __restrict__ Ve) {
    int idx = blockIdx.x * 256 + threadIdx.x;   // b*M + m
    int b = idx >> 11, m = idx & (Mm - 1);
    float mx = NEG_INIT, sm = 0.f;
#pragma unroll
    for (int ch = 0; ch < NCH; ch++) {
        float om = pmx[((size_t)(b * NCH + ch)) * Mm + m];
        float os = psm[((size_t)(b * NCH + ch)) * Mm + m];
        float nm = fmaxf(mx, om);
        sm = sm * exp2f(mx - nm) + os * exp2f(om - nm);
        mx = nm;
    }
    Ve[idx] = logq2[idx] - (mx + log2f(sm));
}

// ---------------- finalize: prob = max gamma, corr = (gamma@tgt)/clip(rowsum) ----------------
__global__ __launch_bounds__(256)
void wl_finalize_kernel(const float* __restrict__ Sc, const float* __restrict__ Ue,
                        const float* __restrict__ Ve, const float* __restrict__ tgt,
                        float* __restrict__ prob, float* __restrict__ corr) {
    int w = threadIdx.x >> 6, l = threadIdx.x & 63;
    int row = blockIdx.x * 4 + w;
    int b = row >> 11;
    const float4* s4 = (const float4*)(Sc + (size_t)row * Mm);
    const float4* v4 = (const float4*)(Ve + (size_t)b * Mm);
    const float4* tg4 = (const float4*)(tgt + (size_t)b * Mm * 3);
    float mx = NEG_INIT, sm = 0.f, w0 = 0.f, w1 = 0.f, w2 = 0.f;
#pragma unroll
    for (int i = 0; i < 8; i++) {
        int c = l + 64 * i;
        float4 sv = s4[c]; float4 vv = v4[c];
        float4 g0 = tg4[3 * c + 0], g1 = tg4[3 * c + 1], g2 = tg4[3 * c + 2];
        float tt[4] = { sv.x + vv.x, sv.y + vv.y, sv.z + vv.z, sv.w + vv.w };
        float gx[4] = { g0.x, g0.w, g1.z, g2.y };
        float gy[4] = { g0.y, g1.x, g1.w, g2.z };
        float gz[4] = { g0.z, g1.y, g2.x, g2.w };
#pragma unroll
        for (int j = 0; j < 4; j++) {
            float nm = fmaxf(mx, tt[j]);
            float ce = exp2f(mx - nm), e = exp2f(tt[j] - nm);
            sm = sm * ce + e;
            w0 = w0 * ce + e * gx[j];
            w1 = w1 * ce + e * gy[j];
            w2 = w2 * ce + e * gz[j];
            mx = nm;
        }
    }
    for (int o = 32; o; o >>= 1) {
        float om = __shfl_xor(mx, o), os = __shfl_xor(sm, o);
        float o0 = __shfl_xor(w0, o), o1 = __shfl_xor(w1, o), o2 = __shfl_xor(w2, o);
        float nm = fmaxf(mx, om);
        float c1 = exp2f(mx - nm), c2 = exp2f(om - nm);
        sm = sm * c1 + os * c2;
        w0 = w0 * c1 + o0 * c2;
        w1 = w1 * c1 + o1 * c2;
        w2 = w2 * c1 + o2 * c2;
        mx = nm;
    }
    if (l == 0) {
        float scale = exp2f(Ue[row] + mx);   // = max_m gamma
        float rowsum = scale * sm;
        float den = fmaxf(rowsum, 1e-4f);
        prob[row] = scale;
        corr[(size_t)row * 3 + 0] = scale * w0 / den;
        corr[(size_t)row * 3 + 1] = scale * w1 / den;
        corr[(size_t)row * 3 + 2] = scale * w2 / den;
    }
}

// ---------------- top-k via bitonic sort (best-first) ----------------
__global__ __launch_bounds__(256)
void wl_topk_kernel(const float* __restrict__ prob, int* __restrict__ topk) {
    __shared__ float key[2048];
    __shared__ int val[2048];
    int b = blockIdx.x, t = threadIdx.x;
    for (int i = t; i < 2048; i += 256) { key[i] = prob[b * 2048 + i]; val[i] = i; }
    __syncthreads();
    for (int size = 2; size <= 2048; size <<= 1) {
        for (int stride = size >> 1; stride > 0; stride >>= 1) {
            for (int q = t; q < 1024; q += 256) {
                int i = 2 * q - (q & (stride - 1));
                int j = i + stride;
                bool up = ((i & size) == 0);
                float ki = key[i], kj = key[j];
                int vi = val[i], vj = val[j];
                bool jBetter = (kj > ki) || (kj == ki && vj < vi);
                if (up ? jBetter : !jBetter) {
                    key[i] = kj; key[j] = ki;
                    val[i] = vj; val[j] = vi;
                }
            }
            __syncthreads();
        }
    }
    if (t < TOPK) topk[b * TOPK + t] = val[t];
}

// ---------------- edge Welsch loss per batch ----------------
__global__ __launch_bounds__(256)
void wl_edge_kernel(const float* __restrict__ src, const float* __restrict__ corr,
                    const int* __restrict__ topk, float* __restrict__ bloss) {
    __shared__ float sx[TOPK][3];
    __shared__ float tx[TOPK][3];
    __shared__ float lds[4];
    int b = blockIdx.x, t = threadIdx.x;
    if (t < TOPK) {
        int id = topk[b * TOPK + t];
        sx[t][0] = src[((size_t)b * 2048 + id) * 3 + 0];
        sx[t][1] = src[((size_t)b * 2048 + id) * 3 + 1];
        sx[t][2] = src[((size_t)b * 2048 + id) * 3 + 2];
        tx[t][0] = corr[((size_t)b * 2048 + id) * 3 + 0];
        tx[t][1] = corr[((size_t)b * 2048 + id) * 3 + 1];
        tx[t][2] = corr[((size_t)b * 2048 + id) * 3 + 2];
    }
    __syncthreads();
    float acc = 0.f;
    for (int p = t; p < TOPK * TOPK; p += 256) {
        int i = p >> 7, j = p & 127;
        float dx = sx[i][0] - sx[j][0], dy = sx[i][1] - sx[j][1], dz = sx[i][2] - sx[j][2];
        float d2s = dx * dx + dy * dy + dz * dz;
        float ds = d2s > 0.f ? sqrtf(d2s) : 0.f;
        float ex = tx[i][0] - tx[j][0], ey = tx[i][1] - tx[j][1], ez = tx[i][2] - tx[j][2];
        float d2t = ex * ex + ey * ey + ez * ez;
        float dt = d2t > 0.f ? sqrtf(d2t) : 0.f;
        float z = fabsf(ds - dt);
        acc += 1.f - expf(-0.5f * z * z);
    }
    int l = t & 63, w = t >> 6;
    for (int o = 32; o; o >>= 1) acc += __shfl_xor(acc, o);
    if (l == 0) lds[w] = acc;
    __syncthreads();
    if (t == 0) bloss[b] = lds[0] + lds[1] + lds[2] + lds[3];
}

__global__ void wl_final_kernel(const float* __restrict__ bloss, float* __restrict__ out) {
    if (threadIdx.x == 0) {
        float s = 0.f;
        for (int i = 0; i < Bb; i++) s += bloss[i];
        out[0] = s / 1024.f;   // mean over [B, K] = 8*128
    }
}

extern "C" void kernel_launch(void* const* d_in, const int* in_sizes, int n_in,
                              void* d_out, int out_size, void* d_ws, size_t ws_size,
                              hipStream_t stream) {
    (void)in_sizes; (void)n_in; (void)out_size;
    const float* src       = (const float*)d_in[0];
    const float* tgt       = (const float*)d_in[1];
    const float* src_feats = (const float*)d_in[2];
    const float* tgt_feats = (const float*)d_in[3];
    const float* src_o     = (const float*)d_in[4];
    const float* tgt_o     = (const float*)d_in[5];
    float* out = (float*)d_out;

    // workspace layout (floats)
    float* ws = (float*)d_ws;
    size_t off = 0;
    float* Sc    = ws + off; off += (size_t)Bb * Nn * Mm;        // 33554432
    float* Ue    = ws + off; off += Bb * Nn;
    float* Ve    = ws + off; off += Bb * Mm;
    float* logp2 = ws + off; off += Bb * Nn;
    float* logq2 = ws + off; off += Bb * Mm;
    float* nx    = ws + off; off += Bb * Nn;
    float* ny    = ws + off; off += Bb * Mm;
    float* prob  = ws + off; off += Bb * Nn;
    float* corr  = ws + off; off += (size_t)Bb * Nn * 3;
    float* pmx   = ws + off; off += (size_t)Bb * NCH * Mm;
    float* psm   = ws + off; off += (size_t)Bb * NCH * Mm;
    int*   topk  = (int*)(ws + off); off += Bb * TOPK;
    float* bloss = ws + off; off += Bb;
    if (ws_size < off * sizeof(float)) return;  // insufficient workspace -> fail loudly

    wl_init_kernel<<<Bb, 256, 0, stream>>>(src_o, tgt_o, logp2, logq2, Ve);
    wl_norms_kernel<<<(Bb * Nn) / 4, 256, 0, stream>>>(src_feats, nx);
    wl_norms_kernel<<<(Bb * Mm) / 4, 256, 0, stream>>>(tgt_feats, ny);
    wl_cost_kernel<<<dim3(Mm / BT, Nn / BT, Bb), 256, 0, stream>>>(src_feats, tgt_feats, nx, ny, Sc);

    for (int it = 0; it < SK_ITERS; it++) {
        wl_u_kernel<<<(Bb * Nn) / 4, 256, 0, stream>>>(Sc, Ve, logp2, Ue);
        wl_v_partial_kernel<<<dim3(Mm / 1024, NCH, Bb), 256, 0, stream>>>(Sc, Ue, pmx, psm);
        wl_v_combine_kernel<<<(Bb * Mm) / 256, 256, 0, stream>>>(pmx, psm, logq2, Ve);
    }

    wl_finalize_kernel<<<(Bb * Nn) / 4, 256, 0, stream>>>(Sc, Ue, Ve, tgt, prob, corr);
    wl_topk_kernel<<<Bb, 256, 0, stream>>>(prob, topk);
    wl_edge_kernel<<<Bb, 256, 0, stream>>>(src, corr, topk, bloss);
    wl_final_kernel<<<1, 64, 0, stream>>>(bloss, out);
}